// Round 7
// baseline (152.135 us; speedup 1.0000x reference)
//
#include <hip/hip_runtime.h>
#include <math.h>

// Problem constants (B=8, H=W=32, D=256, heads=4, hd=64)
#define NTOK   1024
#define DMODEL 256
#define NHEADS 4
#define HDIM   64
#define NROWS  8192
#define LOG2E  1.4426950408889634f

typedef __attribute__((ext_vector_type(8))) short          bf16x8;
typedef __attribute__((ext_vector_type(8))) unsigned short ushort8;
typedef __attribute__((ext_vector_type(4))) unsigned short ushort4v;
typedef __attribute__((ext_vector_type(4))) float          f32x4;

__device__ __forceinline__ unsigned short f2bf(float x) {   // RNE fp32->bf16
    unsigned u = __float_as_uint(x);
    u = (u + 0x7fffu + ((u >> 16) & 1u)) >> 16;
    return (unsigned short)u;
}
__device__ __forceinline__ float bf2f(unsigned short u) {
    return __uint_as_float(((unsigned)u) << 16);
}

// ---------------------------------------------------------------------------
// Kernel 1 (prep): V transpose -> Vt[bh][d][key], x cast -> Xb,
// bias expand Pb3, bf16 pre-cast of Wq/Wk/Wo.  Grid (16, 32) x 256.
// ---------------------------------------------------------------------------
__global__ __launch_bounds__(256) void prep(
    const float* __restrict__ X, unsigned short* __restrict__ Vt,
    unsigned short* __restrict__ Xb,
    const float* __restrict__ bt, float* __restrict__ Pb3,
    const float* __restrict__ Wq, const float* __restrict__ Wk,
    const float* __restrict__ Wo,
    unsigned short* __restrict__ Wqb, unsigned short* __restrict__ Wkb,
    unsigned short* __restrict__ Wob)
{
    const int kt = blockIdx.x;    // 0..15 (64-key tile)
    const int bh = blockIdx.y;    // 0..31
    const int b = bh >> 2, h = bh & 3;
    const int t = threadIdx.x;
    __shared__ unsigned short T[64][80];

    const int gid = (blockIdx.y * gridDim.x + blockIdx.x) * 256 + t;  // 0..131071

    // fused bias expansion (61440 elems)
    if (gid < NHEADS * 15 * 1024) {
        const int w2 = gid & 31;
        const int w1 = (gid >> 5) & 31;
        const int rh = (gid >> 10) % 15;
        const int hh = gid / (15 * 1024);
        int rw = w1 - w2 + 7; rw = rw < 0 ? 0 : (rw > 14 ? 14 : rw);
        Pb3[gid] = bt[(rh * 15 + rw) * NHEADS + hh] * LOG2E;
    }

    // fused weight cast: 3 * 65536 elems = 24576 ushort8 granules
    if (gid < 3 * 8192) {
        const int which = gid >> 13;          // 0=Wq 1=Wk 2=Wo
        const int off   = (gid & 8191) * 8;
        const float* __restrict__ Ws = which == 0 ? Wq : (which == 1 ? Wk : Wo);
        unsigned short* __restrict__ Wd = which == 0 ? Wqb : (which == 1 ? Wkb : Wob);
        const float4 w0 = *(const float4*)&Ws[off];
        const float4 w1 = *(const float4*)&Ws[off + 4];
        ushort8 pk;
        pk[0]=f2bf(w0.x); pk[1]=f2bf(w0.y); pk[2]=f2bf(w0.z); pk[3]=f2bf(w0.w);
        pk[4]=f2bf(w1.x); pk[5]=f2bf(w1.y); pk[6]=f2bf(w1.z); pk[7]=f2bf(w1.w);
        *(ushort8*)&Wd[off] = pk;
    }

    #pragma unroll
    for (int i = 0; i < 4; i++) {
        const int tt  = t + 256 * i;       // 0..1023
        const int key = tt >> 4;           // 0..63
        const int d4  = (tt & 15) * 4;
        const long off = (long)(b*NTOK + kt*64 + key)*DMODEL + h*HDIM + d4;
        const float4 v = *(const float4*)&X[off];
        ushort4v pk;
        pk.x = f2bf(v.x); pk.y = f2bf(v.y); pk.z = f2bf(v.z); pk.w = f2bf(v.w);
        *(ushort4v*)&Xb[off] = pk;          // linear bf16 copy of x
        T[d4+0][key] = pk.x; T[d4+1][key] = pk.y;
        T[d4+2][key] = pk.z; T[d4+3][key] = pk.w;
    }
    __syncthreads();
    #pragma unroll
    for (int i = 0; i < 2; i++) {
        const int tt = t + 256 * i;        // 0..511
        const int d  = tt >> 3;            // 0..63
        const int g  = tt & 7;             // 0..7
        const ushort8 o = *(const ushort8*)&T[d][g*8];
        *(ushort8*)&Vt[(bh*HDIM + d)*NTOK + kt*64 + g*8] = o;
    }
}

// ---------------------------------------------------------------------------
// Kernel 2: MFMA projection GEMM.  C = Xb @ Wb^T (+bias) [* scale] -> bf16
// Tile 128(M) x 64(N), 4 waves.  Wb (bf16) staged once in LDS.
// blockIdx.z: 0 -> Q (scale 0.125*log2e), 1 -> K.
// ---------------------------------------------------------------------------
__global__ __launch_bounds__(256) void gemm_proj_mfma(
    const unsigned short* __restrict__ Xb,
    const unsigned short* __restrict__ Wqb, const float* __restrict__ bq,
    const unsigned short* __restrict__ Wkb, const float* __restrict__ bk,
    unsigned short* __restrict__ Qb, unsigned short* __restrict__ Kb)
{
    const int zz = blockIdx.z;
    const unsigned short* __restrict__ Wb = zz ? Wkb : Wqb;
    const float* __restrict__ bias = zz ? bk : bq;
    unsigned short* __restrict__ C = zz ? Kb : Qb;
    const float scale = zz ? 1.0f : (0.125f * LOG2E);

    const int n0 = blockIdx.x * 64;
    const int m0 = blockIdx.y * 128;
    const int t  = threadIdx.x;
    const int wv = t >> 6, lane = t & 63;
    const int quad = lane >> 4, l16 = lane & 15;

    __shared__ unsigned short Bs[64 * 256];   // 32 KB, swizzled 16B granules

    #pragma unroll
    for (int i = 0; i < 8; i++) {
        const int tt = t + 256 * i;           // 0..2047
        const int n  = tt >> 5;               // 0..63
        const int g  = tt & 31;               // granule (8 bf16)
        const ushort8 v = *(const ushort8*)&Wb[(n0 + n)*DMODEL + g*8];
        *(ushort8*)&Bs[n*256 + 8*(g ^ (n & 7))] = v;
    }
    __syncthreads();

    const int rowbase = m0 + wv * 32;

    f32x4 acc[2][4];
    #pragma unroll
    for (int nf = 0; nf < 4; nf++) {
        const float bv = bias[n0 + nf*16 + l16];
        #pragma unroll
        for (int mf = 0; mf < 2; mf++) { acc[mf][nf] = (f32x4){bv,bv,bv,bv}; }
    }

    for (int ks = 0; ks < 8; ks++) {
        const bf16x8 a0 = *(const bf16x8*)&Xb[(rowbase      + l16)*DMODEL + ks*32 + quad*8];
        const bf16x8 a1 = *(const bf16x8*)&Xb[(rowbase + 16 + l16)*DMODEL + ks*32 + quad*8];
        #pragma unroll
        for (int nf = 0; nf < 4; nf++) {
            const int n = nf*16 + l16;
            const bf16x8 bfr = *(const bf16x8*)&Bs[n*256 + 8*((ks*4 + quad) ^ (n & 7))];
            acc[0][nf] = __builtin_amdgcn_mfma_f32_16x16x32_bf16(a0, bfr, acc[0][nf], 0, 0, 0);
            acc[1][nf] = __builtin_amdgcn_mfma_f32_16x16x32_bf16(a1, bfr, acc[1][nf], 0, 0, 0);
        }
    }

    #pragma unroll
    for (int mf = 0; mf < 2; mf++)
        #pragma unroll
        for (int nf = 0; nf < 4; nf++) {
            const int col = n0 + nf*16 + l16;
            #pragma unroll
            for (int r = 0; r < 4; r++) {
                const int row = rowbase + mf*16 + quad*4 + r;
                C[row*DMODEL + col] = f2bf(acc[mf][nf][r] * scale);
            }
        }
}

// ---------------------------------------------------------------------------
// Kernel 3: MFMA flash attention, split-K (2 halves of 512 keys), slim LDS.
// Grid (16 qtiles, 32 bh, 2 halves) = 1024 blocks, 256 thr.
// LDS: Ks (16 KB, shared across waves) + Ps (17 KB) = 33 KB -> 4 blocks/CU.
// V B-fragments read DIRECTLY from global Vt (L1/L2-resident, 16B/lane).
// Writes UNNORMALIZED bf16 partial O + per-row partial sums.
// ---------------------------------------------------------------------------
__global__ __launch_bounds__(256, 4) void attn_mfma(
    const unsigned short* __restrict__ Qb, const unsigned short* __restrict__ Kb,
    const unsigned short* __restrict__ Vt, const float* __restrict__ Pb3,
    unsigned short* __restrict__ Op0, unsigned short* __restrict__ Op1,
    float* __restrict__ rsum)
{
    const int qt   = blockIdx.x;    // 0..15
    const int bh   = blockIdx.y;    // 0..31
    const int half = blockIdx.z;    // 0..1
    const int b    = bh >> 2, h = bh & 3;
    const int t    = threadIdx.x;
    const int wv   = t >> 6, lane = t & 63;
    const int quad = lane >> 4, l16 = lane & 15;

    __shared__ unsigned short Ks[128 * 64];     // 16 KB
    __shared__ unsigned short Ps[4][16 * 136];  // 17 KB (per-wave P round-trip)

    const int qbase = qt * 64 + wv * 16;
    const int h1    = qbase >> 5;               // wave-uniform
    const int w1    = (qbase & 31) + l16;

    bf16x8 qa0, qa1;
    {
        const unsigned short* qp =
            &Qb[(b*NTOK + qbase + l16) * DMODEL + h*HDIM + quad*8];
        qa0 = *(const bf16x8*)(qp);
        qa1 = *(const bf16x8*)(qp + 32);
    }

    f32x4 Of[4] = {};
    float rs = 0.f;

    const unsigned short* KbBase = &Kb[(b*NTOK) * DMODEL + h*HDIM];
    const unsigned short* VtBase = &Vt[(bh*HDIM) * NTOK];
    unsigned short* Pw = Ps[wv];
    const int cbase = half * 512;

    // prefetch first K chunk of this half
    ushort8 kpre[4];
    #pragma unroll
    for (int i = 0; i < 4; i++) {
        const int tt = t + 256*i;
        kpre[i] = *(const ushort8*)&KbBase[(cbase + (tt >> 3))*DMODEL + (tt & 7)*8];
    }

    for (int ch = 0; ch < 4; ch++) {
        const int c0 = cbase + ch * 128;
        __syncthreads();
        #pragma unroll
        for (int i = 0; i < 4; i++) {
            const int tt = t + 256*i;
            const int key = tt >> 3, g = tt & 7;
            *(ushort8*)&Ks[key*64 + 8*(g ^ (key & 7))] = kpre[i];
        }
        __syncthreads();
        if (ch < 3) {     // next chunk's K loads overlap compute below
            const int nx = c0 + 128;
            #pragma unroll
            for (int i = 0; i < 4; i++) {
                const int tt = t + 256*i;
                kpre[i] = *(const ushort8*)&KbBase[(nx + (tt >> 3))*DMODEL + (tt & 7)*8];
            }
        }

        // ---- scores: S^T tile = K_tile @ Q^T, bias preloaded in acc ----
        #pragma unroll
        for (int nt = 0; nt < 8; nt++) {
            const int nk = c0 + nt*16;
            const int h2 = nk >> 5;
            int rh = h1 - h2 + 7; rh = rh < 0 ? 0 : (rh > 14 ? 14 : rh);
            const int w2b = (nk & 31) + quad*4;
            f32x4 c = *(const f32x4*)&Pb3[(((h*15 + rh)*32) + w1)*32 + w2b];
            const int kk = nt*16 + l16;
            {
                const bf16x8 ka = *(const bf16x8*)&Ks[kk*64 + 8*(quad ^ (kk & 7))];
                c = __builtin_amdgcn_mfma_f32_16x16x32_bf16(ka, qa0, c, 0, 0, 0);
            }
            {
                const bf16x8 ka = *(const bf16x8*)&Ks[kk*64 + 8*((quad+4) ^ (kk & 7))];
                c = __builtin_amdgcn_mfma_f32_16x16x32_bf16(ka, qa1, c, 0, 0, 0);
            }
            const float p0 = exp2f(c[0]), p1 = exp2f(c[1]);
            const float p2 = exp2f(c[2]), p3 = exp2f(c[3]);
            rs += (p0 + p1) + (p2 + p3);
            uint2 pk;
            pk.x = (unsigned)f2bf(p0) | ((unsigned)f2bf(p1) << 16);
            pk.y = (unsigned)f2bf(p2) | ((unsigned)f2bf(p3) << 16);
            *(uint2*)&Pw[l16*136 + nt*16 + quad*4] = pk;
        }
        __threadfence_block();   // order P LDS writes before A-frag reads

        // ---- PV: O += P V ; V B-frags straight from global (L1-resident) ----
        #pragma unroll
        for (int ks = 0; ks < 4; ks++) {
            const bf16x8 pa = *(const bf16x8*)&Pw[l16*136 + ks*32 + quad*8];
            #pragma unroll
            for (int dt = 0; dt < 4; dt++) {
                const bf16x8 vb = *(const bf16x8*)
                    &VtBase[(dt*16 + l16)*NTOK + c0 + ks*32 + quad*8];
                Of[dt] = __builtin_amdgcn_mfma_f32_16x16x32_bf16(pa, vb, Of[dt], 0, 0, 0);
            }
        }
    }

    // ---- epilogue: partial row sums + unnormalized bf16 partial O ----
    float tot = rs;
    tot += __shfl_xor(tot, 16);
    tot += __shfl_xor(tot, 32);          // full half-sum for q-row l16
    if (quad == 0)
        rsum[(half*32 + bh)*NTOK + qbase + l16] = tot;

    unsigned short* __restrict__ Op = half ? Op1 : Op0;
    #pragma unroll
    for (int dt = 0; dt < 4; dt++)
        #pragma unroll
        for (int r = 0; r < 4; r++) {
            const int row = qbase + quad*4 + r;
            Op[(b*NTOK + row)*DMODEL + h*HDIM + dt*16 + l16] = f2bf(Of[dt][r]);
        }
}

// ---------------------------------------------------------------------------
// Kernel 4: MFMA output projection + gated blend, with FUSED split-K combine:
// A-frag = (Op0 + Op1) * rinv[head]  built in-register (no combine kernel).
// out = x + (1-g)*pe + g*(O @ Wo^T + bo), fp32 out.  64x64 tile, 512 blocks.
// ---------------------------------------------------------------------------
__global__ __launch_bounds__(256) void gemm_out_mfma(
    const unsigned short* __restrict__ Op0, const unsigned short* __restrict__ Op1,
    const float* __restrict__ rsum,
    const unsigned short* __restrict__ Wob, const float* __restrict__ bo,
    const float* __restrict__ X, const float* __restrict__ PE,
    const float* __restrict__ gatep,
    float* __restrict__ Out)
{
    const int n0 = blockIdx.x * 64;
    const int m0 = blockIdx.y * 64;
    const int t  = threadIdx.x;
    const int wv = t >> 6, lane = t & 63;
    const int quad = lane >> 4, l16 = lane & 15;

    __shared__ unsigned short Bs[64 * 256];

    #pragma unroll
    for (int i = 0; i < 8; i++) {
        const int tt = t + 256 * i;
        const int n  = tt >> 5;
        const int g  = tt & 31;
        const ushort8 v = *(const ushort8*)&Wob[(n0 + n)*DMODEL + g*8];
        *(ushort8*)&Bs[n*256 + 8*(g ^ (n & 7))] = v;
    }
    __syncthreads();

    const int rowbase = m0 + wv * 16;
    const int arow = rowbase + l16;          // this lane's A row
    const int ab = arow >> 10, an = arow & 1023;

    // per-head 1/(l0+l1) for this row
    float rinv4[4];
    #pragma unroll
    for (int hh = 0; hh < 4; hh++) {
        const float l0 = rsum[(      ab*NHEADS + hh)*NTOK + an];
        const float l1 = rsum[(32 +  ab*NHEADS + hh)*NTOK + an];
        rinv4[hh] = 1.0f / (l0 + l1);
    }

    f32x4 acc[4];
    #pragma unroll
    for (int nf = 0; nf < 4; nf++) {
        const float bv = bo[n0 + nf*16 + l16];
        acc[nf] = (f32x4){bv,bv,bv,bv};
    }

    for (int ks = 0; ks < 8; ks++) {
        const float ri = rinv4[ks >> 1];     // head = (ks*32)/64
        const ushort8 p0 = *(const ushort8*)&Op0[arow*DMODEL + ks*32 + quad*8];
        const ushort8 p1 = *(const ushort8*)&Op1[arow*DMODEL + ks*32 + quad*8];
        bf16x8 a0;
        #pragma unroll
        for (int j = 0; j < 8; j++)
            a0[j] = (short)f2bf((bf2f(p0[j]) + bf2f(p1[j])) * ri);
        #pragma unroll
        for (int nf = 0; nf < 4; nf++) {
            const int n = nf*16 + l16;
            const bf16x8 bfr = *(const bf16x8*)&Bs[n*256 + 8*((ks*4 + quad) ^ (n & 7))];
            acc[nf] = __builtin_amdgcn_mfma_f32_16x16x32_bf16(a0, bfr, acc[nf], 0, 0, 0);
        }
    }

    const float g  = 1.f / (1.f + __expf(-gatep[0]));
    const float og = 1.f - g;

    #pragma unroll
    for (int nf = 0; nf < 4; nf++) {
        const int col = n0 + nf*16 + l16;
        #pragma unroll
        for (int r = 0; r < 4; r++) {
            const int row = rowbase + quad*4 + r;
            const float xv  = X [row*DMODEL + col];
            const float pev = PE[row*DMODEL + col];
            Out[row*DMODEL + col] = xv + og * pev + g * acc[nf][r];
        }
    }
}

// ---------------------------------------------------------------------------
extern "C" void kernel_launch(void* const* d_in, const int* in_sizes, int n_in,
                              void* d_out, int out_size, void* d_ws, size_t ws_size,
                              hipStream_t stream)
{
    const float* x    = (const float*)d_in[0];
    const float* pe   = (const float*)d_in[1];
    const float* Wq   = (const float*)d_in[2];
    const float* bq   = (const float*)d_in[3];
    const float* Wk   = (const float*)d_in[4];
    const float* bk   = (const float*)d_in[5];
    const float* Wo   = (const float*)d_in[6];
    const float* bo   = (const float*)d_in[7];
    const float* bt   = (const float*)d_in[8];
    const float* gate = (const float*)d_in[9];
    float* out = (float*)d_out;

    char* w = (char*)d_ws;
    const size_t MB = 1024u*1024u;
    unsigned short* Qb  = (unsigned short*)(w);               // 4 MB
    unsigned short* Kb  = (unsigned short*)(w + 4*MB);        // 4 MB
    unsigned short* Vtb = (unsigned short*)(w + 8*MB);        // 4 MB
    unsigned short* Xb  = (unsigned short*)(w + 12*MB);       // 4 MB
    float*          Pb3 = (float*)(w + 16*MB);                // 240 KB (rsvd 256K)
    unsigned short* Wqb = (unsigned short*)(w + 16*MB + 256u*1024);  // 128 KB
    unsigned short* Wkb = (unsigned short*)(w + 16*MB + 384u*1024);  // 128 KB
    unsigned short* Wob = (unsigned short*)(w + 16*MB + 512u*1024);  // 128 KB
    float*          rsum= (float*)(w + 16*MB + 640u*1024);           // 256 KB
    unsigned short* Op0 = (unsigned short*)(w + 17*MB);       // 4 MB
    unsigned short* Op1 = (unsigned short*)(w + 21*MB);       // 4 MB

    prep<<<dim3(16, 32), 256, 0, stream>>>(
        x, Vtb, Xb, bt, Pb3, Wq, Wk, Wo, Wqb, Wkb, Wob);

    gemm_proj_mfma<<<dim3(DMODEL/64, NROWS/128, 2), 256, 0, stream>>>(
        Xb, Wqb, bq, Wkb, bk, Qb, Kb);

    attn_mfma<<<dim3(16, 32, 2), 256, 0, stream>>>(
        Qb, Kb, Vtb, Pb3, Op0, Op1, rsum);

    gemm_out_mfma<<<dim3(DMODEL/64, NROWS/64), 256, 0, stream>>>(
        Op0, Op1, rsum, Wob, bo, x, pe, gate, out);
}

// Round 8
// 130.340 us; speedup vs baseline: 1.1672x; 1.1672x over previous
//
#include <hip/hip_runtime.h>
#include <math.h>

// Problem constants (B=8, H=W=32, D=256, heads=4, hd=64)
#define NTOK   1024
#define DMODEL 256
#define NHEADS 4
#define HDIM   64
#define NROWS  8192
#define LOG2E  1.4426950408889634f

typedef __attribute__((ext_vector_type(8))) short          bf16x8;
typedef __attribute__((ext_vector_type(8))) unsigned short ushort8;
typedef __attribute__((ext_vector_type(4))) unsigned short ushort4v;
typedef __attribute__((ext_vector_type(4))) float          f32x4;

__device__ __forceinline__ unsigned short f2bf(float x) {   // RNE fp32->bf16
    unsigned u = __float_as_uint(x);
    u = (u + 0x7fffu + ((u >> 16) & 1u)) >> 16;
    return (unsigned short)u;
}

// ---------------------------------------------------------------------------
// Kernel 1 (prep): V transpose -> Vt[bh][d][key], x cast -> Xb,
// bias expand Pb3, bf16 pre-cast of Wq/Wk/Wo.  Grid (16, 32) x 256.
// ---------------------------------------------------------------------------
__global__ __launch_bounds__(256) void prep(
    const float* __restrict__ X, unsigned short* __restrict__ Vt,
    unsigned short* __restrict__ Xb,
    const float* __restrict__ bt, float* __restrict__ Pb3,
    const float* __restrict__ Wq, const float* __restrict__ Wk,
    const float* __restrict__ Wo,
    unsigned short* __restrict__ Wqb, unsigned short* __restrict__ Wkb,
    unsigned short* __restrict__ Wob)
{
    const int kt = blockIdx.x;    // 0..15 (64-key tile)
    const int bh = blockIdx.y;    // 0..31
    const int b = bh >> 2, h = bh & 3;
    const int t = threadIdx.x;
    __shared__ unsigned short T[64][80];

    const int gid = (blockIdx.y * gridDim.x + blockIdx.x) * 256 + t;  // 0..131071

    // fused bias expansion (61440 elems)
    if (gid < NHEADS * 15 * 1024) {
        const int w2 = gid & 31;
        const int w1 = (gid >> 5) & 31;
        const int rh = (gid >> 10) % 15;
        const int hh = gid / (15 * 1024);
        int rw = w1 - w2 + 7; rw = rw < 0 ? 0 : (rw > 14 ? 14 : rw);
        Pb3[gid] = bt[(rh * 15 + rw) * NHEADS + hh] * LOG2E;
    }

    // fused weight cast: 3 * 65536 elems = 24576 ushort8 granules
    if (gid < 3 * 8192) {
        const int which = gid >> 13;          // 0=Wq 1=Wk 2=Wo
        const int off   = (gid & 8191) * 8;
        const float* __restrict__ Ws = which == 0 ? Wq : (which == 1 ? Wk : Wo);
        unsigned short* __restrict__ Wd = which == 0 ? Wqb : (which == 1 ? Wkb : Wob);
        const float4 w0 = *(const float4*)&Ws[off];
        const float4 w1 = *(const float4*)&Ws[off + 4];
        ushort8 pk;
        pk[0]=f2bf(w0.x); pk[1]=f2bf(w0.y); pk[2]=f2bf(w0.z); pk[3]=f2bf(w0.w);
        pk[4]=f2bf(w1.x); pk[5]=f2bf(w1.y); pk[6]=f2bf(w1.z); pk[7]=f2bf(w1.w);
        *(ushort8*)&Wd[off] = pk;
    }

    #pragma unroll
    for (int i = 0; i < 4; i++) {
        const int tt  = t + 256 * i;       // 0..1023
        const int key = tt >> 4;           // 0..63
        const int d4  = (tt & 15) * 4;
        const long off = (long)(b*NTOK + kt*64 + key)*DMODEL + h*HDIM + d4;
        const float4 v = *(const float4*)&X[off];
        ushort4v pk;
        pk.x = f2bf(v.x); pk.y = f2bf(v.y); pk.z = f2bf(v.z); pk.w = f2bf(v.w);
        *(ushort4v*)&Xb[off] = pk;          // linear bf16 copy of x
        T[d4+0][key] = pk.x; T[d4+1][key] = pk.y;
        T[d4+2][key] = pk.z; T[d4+3][key] = pk.w;
    }
    __syncthreads();
    #pragma unroll
    for (int i = 0; i < 2; i++) {
        const int tt = t + 256 * i;        // 0..511
        const int d  = tt >> 3;            // 0..63
        const int g  = tt & 7;             // 0..7
        const ushort8 o = *(const ushort8*)&T[d][g*8];
        *(ushort8*)&Vt[(bh*HDIM + d)*NTOK + kt*64 + g*8] = o;
    }
}

// ---------------------------------------------------------------------------
// Kernel 2: MFMA projection GEMM.  C = Xb @ Wb^T (+bias) [* scale] -> bf16
// Tile 128(M) x 64(N), 4 waves.  Wb (bf16) staged once in LDS.
// blockIdx.z: 0 -> Q (scale 0.125*log2e), 1 -> K.
// ---------------------------------------------------------------------------
__global__ __launch_bounds__(256) void gemm_proj_mfma(
    const unsigned short* __restrict__ Xb,
    const unsigned short* __restrict__ Wqb, const float* __restrict__ bq,
    const unsigned short* __restrict__ Wkb, const float* __restrict__ bk,
    unsigned short* __restrict__ Qb, unsigned short* __restrict__ Kb)
{
    const int zz = blockIdx.z;
    const unsigned short* __restrict__ Wb = zz ? Wkb : Wqb;
    const float* __restrict__ bias = zz ? bk : bq;
    unsigned short* __restrict__ C = zz ? Kb : Qb;
    const float scale = zz ? 1.0f : (0.125f * LOG2E);

    const int n0 = blockIdx.x * 64;
    const int m0 = blockIdx.y * 128;
    const int t  = threadIdx.x;
    const int wv = t >> 6, lane = t & 63;
    const int quad = lane >> 4, l16 = lane & 15;

    __shared__ unsigned short Bs[64 * 256];   // 32 KB, swizzled 16B granules

    #pragma unroll
    for (int i = 0; i < 8; i++) {
        const int tt = t + 256 * i;           // 0..2047
        const int n  = tt >> 5;               // 0..63
        const int g  = tt & 31;               // granule (8 bf16)
        const ushort8 v = *(const ushort8*)&Wb[(n0 + n)*DMODEL + g*8];
        *(ushort8*)&Bs[n*256 + 8*(g ^ (n & 7))] = v;
    }
    __syncthreads();

    const int rowbase = m0 + wv * 32;

    f32x4 acc[2][4];
    #pragma unroll
    for (int nf = 0; nf < 4; nf++) {
        const float bv = bias[n0 + nf*16 + l16];
        #pragma unroll
        for (int mf = 0; mf < 2; mf++) { acc[mf][nf] = (f32x4){bv,bv,bv,bv}; }
    }

    for (int ks = 0; ks < 8; ks++) {
        const bf16x8 a0 = *(const bf16x8*)&Xb[(rowbase      + l16)*DMODEL + ks*32 + quad*8];
        const bf16x8 a1 = *(const bf16x8*)&Xb[(rowbase + 16 + l16)*DMODEL + ks*32 + quad*8];
        #pragma unroll
        for (int nf = 0; nf < 4; nf++) {
            const int n = nf*16 + l16;
            const bf16x8 bfr = *(const bf16x8*)&Bs[n*256 + 8*((ks*4 + quad) ^ (n & 7))];
            acc[0][nf] = __builtin_amdgcn_mfma_f32_16x16x32_bf16(a0, bfr, acc[0][nf], 0, 0, 0);
            acc[1][nf] = __builtin_amdgcn_mfma_f32_16x16x32_bf16(a1, bfr, acc[1][nf], 0, 0, 0);
        }
    }

    #pragma unroll
    for (int mf = 0; mf < 2; mf++)
        #pragma unroll
        for (int nf = 0; nf < 4; nf++) {
            const int col = n0 + nf*16 + l16;
            #pragma unroll
            for (int r = 0; r < 4; r++) {
                const int row = rowbase + mf*16 + quad*4 + r;
                C[row*DMODEL + col] = f2bf(acc[mf][nf][r] * scale);
            }
        }
}

// ---------------------------------------------------------------------------
// Kernel 3: MFMA flash attention. Grid (16 qtiles of 64, 32 bh), 256 thr.
// Double-buffered Ks/Vs (1 barrier per chunk; staging overlaps compute),
// XOR-swizzled Ps (16 KB) -> total LDS exactly 80 KB (2 blocks/CU).
// Bias f32x4 loads issued at chunk top (latency off the score path).
// S^T layout, max-free softmax, epilogue normalize, bf16 Ob out.
// ---------------------------------------------------------------------------
__global__ __launch_bounds__(256) void attn_mfma(
    const unsigned short* __restrict__ Qb, const unsigned short* __restrict__ Kb,
    const unsigned short* __restrict__ Vt, const float* __restrict__ Pb3,
    unsigned short* __restrict__ Ob)
{
    const int qt   = blockIdx.x;    // 0..15
    const int bh   = blockIdx.y;    // 0..31
    const int b    = bh >> 2, h = bh & 3;
    const int t    = threadIdx.x;
    const int wv   = t >> 6, lane = t & 63;
    const int quad = lane >> 4, l16 = lane & 15;

    __shared__ unsigned short Ks[2][128 * 64];  // 32 KB
    __shared__ unsigned short Vs[2][64 * 128];  // 32 KB
    __shared__ unsigned short Ps[4][16 * 128];  // 16 KB, XOR-swizzled

    const int qbase = qt * 64 + wv * 16;
    const int h1    = qbase >> 5;               // wave-uniform
    const int w1    = (qbase & 31) + l16;

    bf16x8 qa0, qa1;
    {
        const unsigned short* qp =
            &Qb[(b*NTOK + qbase + l16) * DMODEL + h*HDIM + quad*8];
        qa0 = *(const bf16x8*)(qp);
        qa1 = *(const bf16x8*)(qp + 32);
    }

    f32x4 Of[4] = {};
    float rs = 0.f;

    const unsigned short* KbBase = &Kb[(b*NTOK) * DMODEL + h*HDIM];
    const unsigned short* VtBase = &Vt[(bh*HDIM) * NTOK];
    unsigned short* Pw = Ps[wv];

    // prefetch chunk 0 into registers, stage to buffer 0
    ushort8 kpre[4], vpre[4];
    #pragma unroll
    for (int i = 0; i < 4; i++) {
        const int tt = t + 256*i;
        kpre[i] = *(const ushort8*)&KbBase[(tt >> 3)*DMODEL + (tt & 7)*8];
        vpre[i] = *(const ushort8*)&VtBase[(tt >> 4)*NTOK + (tt & 15)*8];
    }
    #pragma unroll
    for (int i = 0; i < 4; i++) {
        const int tt = t + 256*i;
        const int key = tt >> 3, g = tt & 7;
        *(ushort8*)&Ks[0][key*64 + 8*(g ^ (key & 7))] = kpre[i];
    }
    #pragma unroll
    for (int i = 0; i < 4; i++) {
        const int tt = t + 256*i;
        const int d = tt >> 4, gk = tt & 15;
        *(ushort8*)&Vs[0][d*128 + 8*(gk ^ (d & 7))] = vpre[i];
    }
    __syncthreads();

    for (int ch = 0; ch < 8; ch++) {
        const int c0 = ch * 128;
        const int p  = ch & 1;

        // issue global loads for chunk ch+1 (consumed at staging, bottom)
        if (ch < 7) {
            const int nx = c0 + 128;
            #pragma unroll
            for (int i = 0; i < 4; i++) {
                const int tt = t + 256*i;
                kpre[i] = *(const ushort8*)&KbBase[(nx + (tt >> 3))*DMODEL + (tt & 7)*8];
                vpre[i] = *(const ushort8*)&VtBase[(tt >> 4)*NTOK + nx + (tt & 15)*8];
            }
        }

        // issue all 8 bias loads for this chunk up-front
        f32x4 bias_c[8];
        #pragma unroll
        for (int nt = 0; nt < 8; nt++) {
            const int nk = c0 + nt*16;
            const int h2 = nk >> 5;
            int rh = h1 - h2 + 7; rh = rh < 0 ? 0 : (rh > 14 ? 14 : rh);
            bias_c[nt] = *(const f32x4*)
                &Pb3[(((h*15 + rh)*32) + w1)*32 + (nk & 31) + quad*4];
        }

        // ---- scores: S^T tile = K_tile @ Q^T, bias preloaded in acc ----
        #pragma unroll
        for (int nt = 0; nt < 8; nt++) {
            f32x4 c = bias_c[nt];
            const int kk = nt*16 + l16;
            {
                const bf16x8 ka = *(const bf16x8*)&Ks[p][kk*64 + 8*(quad ^ (kk & 7))];
                c = __builtin_amdgcn_mfma_f32_16x16x32_bf16(ka, qa0, c, 0, 0, 0);
            }
            {
                const bf16x8 ka = *(const bf16x8*)&Ks[p][kk*64 + 8*((quad+4) ^ (kk & 7))];
                c = __builtin_amdgcn_mfma_f32_16x16x32_bf16(ka, qa1, c, 0, 0, 0);
            }
            const float p0 = exp2f(c[0]), p1 = exp2f(c[1]);
            const float p2 = exp2f(c[2]), p3 = exp2f(c[3]);
            rs += (p0 + p1) + (p2 + p3);
            uint2 pk;
            pk.x = (unsigned)f2bf(p0) | ((unsigned)f2bf(p1) << 16);
            pk.y = (unsigned)f2bf(p2) | ((unsigned)f2bf(p3) << 16);
            // P^T->P store: row=qrow=l16, keys nt*16+quad*4..+3 (swizzled granule)
            const int g = nt*2 + (quad >> 1);
            *(uint2*)&Pw[l16*128 + 8*(g ^ l16) + (quad & 1)*4] = pk;
        }
        __threadfence_block();   // order P LDS writes before A-frag reads

        // ---- PV: O += P V ----
        #pragma unroll
        for (int ks = 0; ks < 4; ks++) {
            const bf16x8 pa = *(const bf16x8*)&Pw[l16*128 + 8*((ks*4 + quad) ^ l16)];
            #pragma unroll
            for (int dt = 0; dt < 4; dt++) {
                const int dcol = dt*16 + l16;
                const bf16x8 vb = *(const bf16x8*)
                    &Vs[p][dcol*128 + 8*((ks*4 + quad) ^ (dcol & 7))];
                Of[dt] = __builtin_amdgcn_mfma_f32_16x16x32_bf16(pa, vb, Of[dt], 0, 0, 0);
            }
        }

        // ---- stage chunk ch+1 into the other buffer (overlaps PV tail) ----
        if (ch < 7) {
            #pragma unroll
            for (int i = 0; i < 4; i++) {
                const int tt = t + 256*i;
                const int key = tt >> 3, g = tt & 7;
                *(ushort8*)&Ks[p^1][key*64 + 8*(g ^ (key & 7))] = kpre[i];
            }
            #pragma unroll
            for (int i = 0; i < 4; i++) {
                const int tt = t + 256*i;
                const int d = tt >> 4, gk = tt & 15;
                *(ushort8*)&Vs[p^1][d*128 + 8*(gk ^ (d & 7))] = vpre[i];
            }
            __syncthreads();
        }
    }

    // ---- epilogue: combine quad partial sums, normalize, store bf16 ----
    float tot = rs;
    tot += __shfl_xor(tot, 16);
    tot += __shfl_xor(tot, 32);          // all quads hold row-sum for q-row l16
    float rinv[4];
    #pragma unroll
    for (int r = 0; r < 4; r++)
        rinv[r] = 1.0f / __shfl(tot, quad*4 + r);

    #pragma unroll
    for (int dt = 0; dt < 4; dt++)
        #pragma unroll
        for (int r = 0; r < 4; r++) {
            const int row = qbase + quad*4 + r;
            Ob[(b*NTOK + row)*DMODEL + h*HDIM + dt*16 + l16] = f2bf(Of[dt][r] * rinv[r]);
        }
}

// ---------------------------------------------------------------------------
// Kernel 4: MFMA output projection + gated blend.  64x64 tile (512 blocks).
// out = x + (1-g)*pe + g*(Ob @ Wo^T + bo), fp32 out.
// ---------------------------------------------------------------------------
__global__ __launch_bounds__(256) void gemm_out_mfma(
    const unsigned short* __restrict__ Ob,
    const unsigned short* __restrict__ Wob, const float* __restrict__ bo,
    const float* __restrict__ X, const float* __restrict__ PE,
    const float* __restrict__ gatep,
    float* __restrict__ Out)
{
    const int n0 = blockIdx.x * 64;
    const int m0 = blockIdx.y * 64;
    const int t  = threadIdx.x;
    const int wv = t >> 6, lane = t & 63;
    const int quad = lane >> 4, l16 = lane & 15;

    __shared__ unsigned short Bs[64 * 256];

    #pragma unroll
    for (int i = 0; i < 8; i++) {
        const int tt = t + 256 * i;
        const int n  = tt >> 5;
        const int g  = tt & 31;
        const ushort8 v = *(const ushort8*)&Wob[(n0 + n)*DMODEL + g*8];
        *(ushort8*)&Bs[n*256 + 8*(g ^ (n & 7))] = v;
    }
    __syncthreads();

    const int rowbase = m0 + wv * 16;

    f32x4 acc[4];
    #pragma unroll
    for (int nf = 0; nf < 4; nf++) {
        const float bv = bo[n0 + nf*16 + l16];
        acc[nf] = (f32x4){bv,bv,bv,bv};
    }

    for (int ks = 0; ks < 8; ks++) {
        const bf16x8 a0 = *(const bf16x8*)&Ob[(rowbase + l16)*DMODEL + ks*32 + quad*8];
        #pragma unroll
        for (int nf = 0; nf < 4; nf++) {
            const int n = nf*16 + l16;
            const bf16x8 bfr = *(const bf16x8*)&Bs[n*256 + 8*((ks*4 + quad) ^ (n & 7))];
            acc[nf] = __builtin_amdgcn_mfma_f32_16x16x32_bf16(a0, bfr, acc[nf], 0, 0, 0);
        }
    }

    const float g  = 1.f / (1.f + __expf(-gatep[0]));
    const float og = 1.f - g;

    #pragma unroll
    for (int nf = 0; nf < 4; nf++) {
        const int col = n0 + nf*16 + l16;
        #pragma unroll
        for (int r = 0; r < 4; r++) {
            const int row = rowbase + quad*4 + r;
            const float xv  = X [row*DMODEL + col];
            const float pev = PE[row*DMODEL + col];
            Out[row*DMODEL + col] = xv + og * pev + g * acc[nf][r];
        }
    }
}

// ---------------------------------------------------------------------------
extern "C" void kernel_launch(void* const* d_in, const int* in_sizes, int n_in,
                              void* d_out, int out_size, void* d_ws, size_t ws_size,
                              hipStream_t stream)
{
    const float* x    = (const float*)d_in[0];
    const float* pe   = (const float*)d_in[1];
    const float* Wq   = (const float*)d_in[2];
    const float* bq   = (const float*)d_in[3];
    const float* Wk   = (const float*)d_in[4];
    const float* bk   = (const float*)d_in[5];
    const float* Wo   = (const float*)d_in[6];
    const float* bo   = (const float*)d_in[7];
    const float* bt   = (const float*)d_in[8];
    const float* gate = (const float*)d_in[9];
    float* out = (float*)d_out;

    char* w = (char*)d_ws;
    const size_t MB = 1024u*1024u;
    unsigned short* Qb  = (unsigned short*)(w);               // 4 MB
    unsigned short* Kb  = (unsigned short*)(w + 4*MB);        // 4 MB
    unsigned short* Vtb = (unsigned short*)(w + 8*MB);        // 4 MB
    unsigned short* Xb  = (unsigned short*)(w + 12*MB);       // 4 MB
    float*          Pb3 = (float*)(w + 16*MB);                // 240 KB (rsvd 256K)
    unsigned short* Wqb = (unsigned short*)(w + 16*MB + 256u*1024);  // 128 KB
    unsigned short* Wkb = (unsigned short*)(w + 16*MB + 384u*1024);  // 128 KB
    unsigned short* Wob = (unsigned short*)(w + 16*MB + 512u*1024);  // 128 KB
    unsigned short* Ob  = (unsigned short*)(w + 17*MB);       // 4 MB

    prep<<<dim3(16, 32), 256, 0, stream>>>(
        x, Vtb, Xb, bt, Pb3, Wq, Wk, Wo, Wqb, Wkb, Wob);

    gemm_proj_mfma<<<dim3(DMODEL/64, NROWS/128, 2), 256, 0, stream>>>(
        Xb, Wqb, bq, Wkb, bk, Qb, Kb);

    attn_mfma<<<dim3(16, 32), 256, 0, stream>>>(
        Qb, Kb, Vtb, Pb3, Ob);

    gemm_out_mfma<<<dim3(DMODEL/64, NROWS/64), 256, 0, stream>>>(
        Ob, Wob, bo, x, pe, gate, out);
}